// Round 7
// baseline (317.262 us; speedup 1.0000x reference)
//
#include <hip/hip_runtime.h>
#include <cstdint>

// LeNet-5 forward, B=16384. Batch-lane design: lane = sample, wave-uniform
// control, [feature][N] SoA layouts (coalesced), f16 pair-packed storage.
// R13 = R12 (proven 298us) + software pipelining of the two MFMA kernels:
//   k_c3s4m: B-fragments double-buffered across q (prefetch q+1's 48
//     ds_read_b32 before q's 24 MFMAs -> compiler emits counted lgkmcnt,
//     LDS latency hidden under MFMA). zmask DELETED: pad slots kp>=90 have
//     zero weights in WPK (k_wpack) and clamped LDS reads are finite, so
//     garbage*0 = 0. ~210 VGPR (2 waves/SIMD, LDS-capped at 2 blocks/CU).
//   k_c1s2m: same treatment (fb[2][4] double buffer, 16 reads/q ahead of
//     4 MFMAs).
//   All other kernels byte-identical to R12.
// Plans/offsets identical to R12 (Plan A 10 dispatches / Plan B 13).

typedef unsigned int u32;

union U32H2 { u32 u; _Float16 h[2]; };
__device__ __forceinline__ float f16lo(u32 v) { U32H2 a; a.u = v; return (float)a.h[0]; }
__device__ __forceinline__ float f16hi(u32 v) { U32H2 a; a.u = v; return (float)a.h[1]; }
__device__ __forceinline__ u32 packh2(float a, float b) {
    U32H2 x; x.h[0] = (_Float16)a; x.h[1] = (_Float16)b; return x.u;
}

typedef _Float16 h2v __attribute__((ext_vector_type(2)));
typedef _Float16 half8 __attribute__((ext_vector_type(8)));
typedef float f32x4 __attribute__((ext_vector_type(4)));
union U32V2 { u32 u; h2v v; };
union AB8 { u32 u[4]; half8 h; };

#if defined(__has_builtin)
#if __has_builtin(__builtin_amdgcn_fdot2)
#define HAVE_FDOT2 1
#endif
#endif

// c += a.h0*b.h0 + a.h1*b.h1  (f16 mul, f32 accumulate) -> v_dot2_f32_f16
__device__ __forceinline__ float dot2(u32 a, u32 b, float c) {
    U32V2 x, y; x.u = a; y.u = b;
#ifdef HAVE_FDOT2
    return __builtin_amdgcn_fdot2(x.v, y.v, c, false);
#else
    return c + (float)x.v[0] * (float)y.v[0] + (float)x.v[1] * (float)y.v[1];
#endif
}

// A*tanh(S*v), S=2/3: tanh(y) = 1 - 2/(exp(2y)+1), 2y = (4/3)v
__device__ __forceinline__ float tact(float v) {
    float e = __expf(1.3333333333f * v);
    return 1.7159f * (1.0f - 2.0f * __builtin_amdgcn_rcpf(e + 1.0f));
}

// C3 connectivity bitmask per oc (bit ic) — from reference CONNECTIONS
__device__ const u32 C3_MB[16] = {
    0x07, 0x0E, 0x1C, 0x38, 0x31, 0x23, 0x0F, 0x1E,
    0x3C, 0x39, 0x33, 0x27, 0x1B, 0x36, 0x2D, 0x3F };

// Weight-pack layout (u32 indices inside WPK):
//  W1P  @0     : [6ch][5ky][3q]  pair = (w[2q], w[2q+1]|0)          (90, pad 96)
//  W1S  @96    : [6ch][5ky][3q]  pair = (0,w0)|(w1,w2)|(w3,w4)      (90, pad 96)
//  W3A  @192   : [16 oc][96 kp]  masked aligned, kp=(ic*5+kr)*3+pr,
//                                kp 90..95 = 0                      (1536)
//  W3S  @1728  : [16 oc][96 kp]  masked shifted                     (1536)
//  W5P  @3264  : [120c][80g][3q] pair = (w5[c][g*5+2q], +1|0)       (28800)
//  F6P  @32064 : [84o][60i]      pair = (f6w[o][2i], f6w[o][2i+1])  (5040)
#define WPK_W1  0
#define WPK_W1S 96
#define WPK_W3A 192
#define WPK_W3S 1728
#define WPK_W5  3264
#define WPK_F6  32064
#define WPK_N   37104

__global__ __launch_bounds__(256) void k_wpack(
    const float* __restrict__ w1, const float* __restrict__ w3,
    const float* __restrict__ w5, const float* __restrict__ f6w,
    u32* __restrict__ wpk)
{
    const int idx = blockIdx.x * 256 + threadIdx.x;
    if (idx >= WPK_N) return;
    float a = 0.0f, b = 0.0f;
    if (idx < 192) {                         // w1 aligned / shifted
        const int s = idx >= 96;
        const int t = idx - s * 96;
        if (t < 90) {
            int ch = t / 15, r = t % 15, ky = r / 3, q = r % 3;
            const float* w = w1 + ch * 25 + ky * 5;
            if (!s) { a = w[2 * q]; if (q < 2) b = w[2 * q + 1]; }
            else if (q == 0) { b = w[0]; }
            else { a = w[2 * q - 1]; b = w[2 * q]; }
        }
    } else if (idx < WPK_W5) {               // w3 masked aligned / shifted [oc][96]
        const int t2 = idx - WPK_W3A;
        const int s = t2 >= 1536;
        const int t = t2 - s * 1536;
        const int oc = t / 96, kp = t % 96;
        if (kp < 90) {
            int ic = kp / 15, rem = kp % 15, ky = rem / 3, q = rem % 3;
            if ((C3_MB[oc] >> ic) & 1) {
                const float* w = w3 + (oc * 6 + ic) * 25 + ky * 5;
                if (!s) { a = w[2 * q]; if (q < 2) b = w[2 * q + 1]; }
                else if (q == 0) { b = w[0]; }
                else { a = w[2 * q - 1]; b = w[2 * q]; }
            }
        }
    } else if (idx < WPK_F6) {
        int t = idx - WPK_W5;
        int c = t / 240, r = t % 240, g = r / 3, q = r % 3;
        a = w5[c * 400 + g * 5 + 2 * q];
        if (q < 2) b = w5[c * 400 + g * 5 + 2 * q + 1];
    } else {
        int t = idx - WPK_F6;
        int o = t / 60, i = t % 60;
        a = f6w[o * 120 + 2 * i];
        b = f6w[o * 120 + 2 * i + 1];
    }
    wpk[idx] = packh2(a, b);
}

// ---------------- transpose: x chunk (8192,1024) f32 -> xp u32[512][8192] ---
__global__ __launch_bounds__(256) void k_tr(const float* __restrict__ x,
                                            u32* __restrict__ xp)
{
    __shared__ _Float16 lds[64 * 66];
    const int t = threadIdx.x;
    const int tb = blockIdx.x * 64;          // sample tile
    const int tp = blockIdx.y * 64;          // position tile
    #pragma unroll
    for (int i = 0; i < 16; ++i) {           // coalesced read along positions
        int idx = i * 256 + t;
        int bl = idx >> 6, pl = idx & 63;
        lds[pl * 66 + bl] = (_Float16)x[(size_t)(tb + bl) * 1024 + tp + pl];
    }
    __syncthreads();
    #pragma unroll
    for (int j = 0; j < 8; ++j) {            // coalesced pair-write along batch
        int idx = j * 256 + t;
        int pp = idx >> 6, bl = idx & 63;    // pp in [0,32)
        U32H2 u;
        u.h[0] = lds[(2 * pp) * 66 + bl];
        u.h[1] = lds[(2 * pp + 1) * 66 + bl];
        xp[(size_t)(blockIdx.y * 32 + pp) * 8192 + tb + bl] = u.u;
    }
}

// ---------------- C1 + S2 fused via MFMA, grid (nb/64, 14) ------------------
// Block = 64 samples x one oy2. M rows rho = 2*oc+par (12 used), K = 32
// (kp = ky*3+pr, halves; kp 15 = pad -> zeroed LDS cells), N = 16/wave.
// B-frags double-buffered across q (prefetch q+1 before q's MFMAs).
__global__ __launch_bounds__(256) void k_c1s2m(
    const u32* __restrict__ xp, const u32* __restrict__ wpk,
    const float* __restrict__ b1,
    const float* __restrict__ s2w, const float* __restrict__ s2b,
    u32* __restrict__ s2p, int nxp, int ostr)
{
    __shared__ u32 lds[126 * 65];            // 32,760 B; cells 96..125 zero
    const int t = threadIdx.x;
    const int oy2 = blockIdx.y;
    const int base = blockIdx.x * 64;
    const int y0 = 2 * oy2;

    // zero pad cells 96..125
    for (int i = t; i < 30 * 65; i += 256) lds[96 * 65 + i] = 0;
    // stage XP rows y0*16 .. y0*16+95 x 64 samples (uint2 coalesced)
    {
        const uint2* xp2 = (const uint2*)xp;
        const int nxp2 = nxp >> 1;
        #pragma unroll
        for (int i = 0; i < 12; ++i) {
            int idx = i * 256 + t;           // 96 cells x 32 sample-pairs
            int cell = idx >> 5, sp = idx & 31;
            uint2 v = xp2[(size_t)(y0 * 16 + cell) * nxp2 + (base >> 1) + sp];
            lds[cell * 65 + 2 * sp]     = v.x;
            lds[cell * 65 + 2 * sp + 1] = v.y;
        }
    }

    const int l = t & 63, w = t >> 6;
    const int g = l >> 4, col = l & 15;
    const int sLocal = w * 16 + col;         // this lane's sample (B/C col)
    const int rho = col;                     // A row this lane supplies
    const int ocw = rho >> 1, parw = rho & 1;

    AB8 wA;                                  // A frag: 4 u32 (one k-step)
    #pragma unroll
    for (int m = 0; m < 4; ++m) {
        int kp = 4 * g + m;
        u32 v = 0;
        if (rho < 12 && kp < 15)
            v = wpk[(parw ? WPK_W1S : WPK_W1) + ocw * 15 + kp];
        wA.u[m] = v;
    }

    int voff[4];                             // LDS base per m (u=q=d=0)
    #pragma unroll
    for (int m = 0; m < 4; ++m) {
        int kp = 4 * g + m;
        int c = (kp < 15) ? ((kp / 3) * 16 + kp % 3) : 96;
        voff[m] = c * 65 + sLocal;
    }

    // epilogue params: lane's 4 acc rows = 4g..4g+3 -> ocs 2g, 2g+1
    const int oc0 = 2 * g;
    float b1v0 = 0.f, b1v1 = 0.f, sw0 = 0.f, sb0 = 0.f, sw1 = 0.f, sb1 = 0.f;
    if (g < 3) {
        b1v0 = b1[oc0];     b1v1 = b1[oc0 + 1];
        sw0  = s2w[oc0];    sb0  = s2b[oc0];
        sw1  = s2w[oc0 + 1]; sb1 = s2b[oc0 + 1];
    }

    __syncthreads();

    float va[2][7], vb[2][7];                // per lane-oc: s2 cols 0..6 / 7..13

    AB8 fb[2][4];                            // [buf][frag f = u*2+d]
    // prefetch q=0
    #pragma unroll
    for (int f = 0; f < 4; ++f) {
        const int off = ((f >> 1) * 16 + (f & 1)) * 65;
        #pragma unroll
        for (int m = 0; m < 4; ++m) fb[0][f].u[m] = lds[voff[m] + off];
    }

    #pragma unroll
    for (int q = 0; q < 7; ++q) {
        const int cur = q & 1, nxt = cur ^ 1;
        if (q < 6) {                         // prefetch q+1
            #pragma unroll
            for (int f = 0; f < 4; ++f) {
                const int off = ((f >> 1) * 16 + 2 * (q + 1) + (f & 1)) * 65;
                #pragma unroll
                for (int m = 0; m < 4; ++m) fb[nxt][f].u[m] = lds[voff[m] + off];
            }
        }
        f32x4 a00 = {0.f,0.f,0.f,0.f};       // u=0, d=0: cols 4q,4q+1
        f32x4 a01 = {0.f,0.f,0.f,0.f};       // u=0, d=1: cols 4q+2,4q+3
        f32x4 a10 = {0.f,0.f,0.f,0.f};       // u=1, d=0
        f32x4 a11 = {0.f,0.f,0.f,0.f};       // u=1, d=1
        a00 = __builtin_amdgcn_mfma_f32_16x16x32_f16(wA.h, fb[cur][0].h, a00, 0, 0, 0);
        a01 = __builtin_amdgcn_mfma_f32_16x16x32_f16(wA.h, fb[cur][1].h, a01, 0, 0, 0);
        a10 = __builtin_amdgcn_mfma_f32_16x16x32_f16(wA.h, fb[cur][2].h, a10, 0, 0, 0);
        a11 = __builtin_amdgcn_mfma_f32_16x16x32_f16(wA.h, fb[cur][3].h, a11, 0, 0, 0);

        // pool: acc reg r = 2*(oc-2g)+par; cols d*2+par = 4q..4q+3
        float m00 = 0.25f * (tact(a00[0] + b1v0) + tact(a00[1] + b1v0) +
                             tact(a01[0] + b1v0) + tact(a01[1] + b1v0));
        float m01 = 0.25f * (tact(a00[2] + b1v1) + tact(a00[3] + b1v1) +
                             tact(a01[2] + b1v1) + tact(a01[3] + b1v1));
        float m10 = 0.25f * (tact(a10[0] + b1v0) + tact(a10[1] + b1v0) +
                             tact(a11[0] + b1v0) + tact(a11[1] + b1v0));
        float m11 = 0.25f * (tact(a10[2] + b1v1) + tact(a10[3] + b1v1) +
                             tact(a11[2] + b1v1) + tact(a11[3] + b1v1));
        va[0][q] = tact(sw0 * m00 + sb0);
        vb[0][q] = tact(sw0 * m10 + sb0);
        va[1][q] = tact(sw1 * m01 + sb1);
        vb[1][q] = tact(sw1 * m11 + sb1);
    }

    // store (lanes g<3 own chs 2g, 2g+1): R9 o7 pack into [fh][ostr][2] cells
    if (g < 3) {
        const int sl = base + sLocal;
        #pragma unroll
        for (int a = 0; a < 2; ++a) {
            u32 o7[7];
            o7[0] = packh2(va[a][0], va[a][1]);
            o7[1] = packh2(va[a][2], va[a][3]);
            o7[2] = packh2(va[a][4], va[a][5]);
            o7[3] = packh2(va[a][6], vb[a][0]);
            o7[4] = packh2(vb[a][1], vb[a][2]);
            o7[5] = packh2(vb[a][3], vb[a][4]);
            o7[6] = packh2(vb[a][5], vb[a][6]);
            const int ch = oc0 + a;
            const int f0 = ch * 98 + oy2 * 7;
            const int fh0 = f0 >> 1;
            uint2* p2 = (uint2*)s2p;
            uint2 tt;
            if ((oy2 & 1) == 0) {
                tt.x = o7[0]; tt.y = o7[1]; p2[(size_t)(fh0 + 0) * ostr + sl] = tt;
                tt.x = o7[2]; tt.y = o7[3]; p2[(size_t)(fh0 + 1) * ostr + sl] = tt;
                tt.x = o7[4]; tt.y = o7[5]; p2[(size_t)(fh0 + 2) * ostr + sl] = tt;
                s2p[((size_t)(fh0 + 3) * ostr + sl) * 2] = o7[6];
            } else {
                s2p[((size_t)fh0 * ostr + sl) * 2 + 1] = o7[0];
                tt.x = o7[1]; tt.y = o7[2]; p2[(size_t)(fh0 + 1) * ostr + sl] = tt;
                tt.x = o7[3]; tt.y = o7[4]; p2[(size_t)(fh0 + 2) * ostr + sl] = tt;
                tt.x = o7[5]; tt.y = o7[6]; p2[(size_t)(fh0 + 3) * ostr + sl] = tt;
            }
        }
    }
}

// ---------------- C3 + S4 fused via MFMA, grid (nb/64, 5) -------------------
// R12 structure + double-buffered B-frags (prefetch q+1's 48 reads before
// q's 24 MFMAs). No zmask: pad kp>=90 weights are zero in WPK; clamped LDS
// reads are finite activations -> 0*finite = 0.
__global__ __launch_bounds__(256) void k_c3s4m(
    const u32* __restrict__ s2p, const u32* __restrict__ wpk,
    const float* __restrict__ b3, const float* __restrict__ s4w,
    const float* __restrict__ s4b, u32* __restrict__ s4p, int nb)
{
    __shared__ u32 lds[252 * 65];            // 65,520 B
    const int t = threadIdx.x;
    const int y2 = blockIdx.y;
    const int base = blockIdx.x * 64;        // sample base
    const uint2* s2c = (const uint2*)s2p;

    // ---- stage: 6 ic x 21 uint2 cells x 64 samples (coalesced) ----
    for (int i = 0; i < 32; ++i) {
        int idx = i * 256 + t;
        if (idx < 8064) {
            int ic = idx / 1344;             // 21*64
            int r = idx - ic * 1344;
            int cell = r >> 6, sLoc = r & 63;
            uint2 v = s2c[(size_t)(49 * ic + 7 * y2 + cell) * nb + base + sLoc];
            lds[(ic * 42 + 2 * cell) * 65 + sLoc]     = v.x;
            lds[(ic * 42 + 2 * cell + 1) * 65 + sLoc] = v.y;
        }
    }

    // ---- per-lane setup ----
    const int l = t & 63, w = t >> 6;
    const int g = l >> 4, col = l & 15;
    const int sLocal = w * 16 + col;         // this lane's sample (B/C col)
    const int ocA = col;                     // A row supplied by this lane

    AB8 wA[6], wS[6];                        // A frags: aligned / shifted
    #pragma unroll
    for (int s = 0; s < 6; ++s)
        #pragma unroll
        for (int m = 0; m < 4; ++m) {
            int kp = 16 * s + 4 * g + m;
            wA[s].u[m] = wpk[WPK_W3A + ocA * 96 + kp];
            wS[s].u[m] = wpk[WPK_W3S + ocA * 96 + kp];
        }

    int vbase[6][4];                         // LDS base index per (s,m) slot
    #pragma unroll
    for (int s = 0; s < 6; ++s)
        #pragma unroll
        for (int m = 0; m < 4; ++m) {
            int kp = 16 * s + 4 * g + m;
            int ic = kp / 15;
            int rem = kp - ic * 15;
            int kr = rem / 3;
            int pr = rem - kr * 3;
            int c = ic * 42 + kr * 7 + pr;
            if (kp >= 90) c = 240;           // clamp: weights are 0 there
            vbase[s][m] = c * 65 + sLocal;
        }

    float b3v[4], swv[4], sbv[4];            // epilogue params for oc = 4g+r
    #pragma unroll
    for (int r = 0; r < 4; ++r) {
        b3v[r] = b3[4 * g + r];
        swv[r] = s4w[4 * g + r];
        sbv[r] = s4b[4 * g + r];
    }

    __syncthreads();

    float pool[4][5];
    #pragma unroll
    for (int r = 0; r < 4; ++r)
        #pragma unroll
        for (int x2 = 0; x2 < 5; ++x2) pool[r][x2] = 0.0f;

    AB8 b0[2][6], b1[2][6];                  // double-buffered B-frags
    // prefetch q=0
    #pragma unroll
    for (int s = 0; s < 6; ++s)
        #pragma unroll
        for (int m = 0; m < 4; ++m) {
            b0[0][s].u[m] = lds[vbase[s][m]];
            b1[0][s].u[m] = lds[vbase[s][m] + 7 * 65];
        }

    #pragma unroll
    for (int q = 0; q < 5; ++q) {
        const int cur = q & 1, nxt = cur ^ 1;
        if (q < 4) {                         // prefetch q+1 before q's MFMAs
            #pragma unroll
            for (int s = 0; s < 6; ++s)
                #pragma unroll
                for (int m = 0; m < 4; ++m) {
                    b0[nxt][s].u[m] = lds[vbase[s][m] + (q + 1) * 65];
                    b1[nxt][s].u[m] = lds[vbase[s][m] + (q + 8) * 65];
                }
        }
        f32x4 a00 = {0.f, 0.f, 0.f, 0.f};    // u=0 (row 2y2),   ox=2q
        f32x4 a01 = {0.f, 0.f, 0.f, 0.f};    // u=0,             ox=2q+1
        f32x4 a10 = {0.f, 0.f, 0.f, 0.f};    // u=1 (row 2y2+1), ox=2q
        f32x4 a11 = {0.f, 0.f, 0.f, 0.f};    // u=1,             ox=2q+1
        #pragma unroll
        for (int s = 0; s < 6; ++s) {
            a00 = __builtin_amdgcn_mfma_f32_16x16x32_f16(wA[s].h, b0[cur][s].h, a00, 0, 0, 0);
            a01 = __builtin_amdgcn_mfma_f32_16x16x32_f16(wS[s].h, b0[cur][s].h, a01, 0, 0, 0);
            a10 = __builtin_amdgcn_mfma_f32_16x16x32_f16(wA[s].h, b1[cur][s].h, a10, 0, 0, 0);
            a11 = __builtin_amdgcn_mfma_f32_16x16x32_f16(wS[s].h, b1[cur][s].h, a11, 0, 0, 0);
        }
        // fused tanh + S4 reshape-flat pooling (flat f = u*10 + ox, x2 = f>>2)
        #pragma unroll
        for (int r = 0; r < 4; ++r) {
            pool[r][(2 * q) >> 2]      += tact(a00[r] + b3v[r]);
            pool[r][(2 * q + 1) >> 2]  += tact(a01[r] + b3v[r]);
            pool[r][(10 + 2 * q) >> 2] += tact(a10[r] + b3v[r]);
            pool[r][(11 + 2 * q) >> 2] += tact(a11[r] + b3v[r]);
        }
    }

    // S4 affine + tanh, store in R9 s4p format: u32[(oc*5+y2)*3+j][nb]
    const int sG = base + sLocal;
    #pragma unroll
    for (int r = 0; r < 4; ++r) {
        float so[5];
        #pragma unroll
        for (int x2 = 0; x2 < 5; ++x2)
            so[x2] = tact(0.25f * pool[r][x2] * swv[r] + sbv[r]);
        const int ocr = 4 * g + r;
        const size_t gf = (size_t)(ocr * 5 + y2) * 3;
        s4p[(gf + 0) * nb + sG] = packh2(so[0], so[1]);
        s4p[(gf + 1) * nb + sG] = packh2(so[2], so[3]);
        s4p[(gf + 2) * nb + sG] = packh2(so[4], 0.0f);
    }
}

// ---------------- C5: 120-ch GEMV over 240 s4 pairs, grid (nb/256, 12) ------
__global__ __launch_bounds__(256) void k_c5(
    const u32* __restrict__ s4p, const u32* __restrict__ wpk,
    const float* __restrict__ b5, u32* __restrict__ h5p, int nb)
{
    const int sl = blockIdx.x * 256 + threadIdx.x;
    const int chg = blockIdx.y;              // channels chg*10 .. chg*10+9
    const u32* wp = wpk + WPK_W5 + chg * 10 * 240;
    float acc[10];
    #pragma unroll
    for (int c = 0; c < 10; ++c) acc[c] = b5[chg * 10 + c];
    #pragma unroll 4
    for (int i = 0; i < 240; ++i) {
        const u32 v = s4p[(size_t)i * nb + sl];
        #pragma unroll
        for (int c = 0; c < 10; ++c)
            acc[c] = dot2(v, wp[c * 240 + i], acc[c]);   // uniform -> s_load
    }
    #pragma unroll
    for (int j = 0; j < 5; ++j)
        h5p[(size_t)(chg * 5 + j) * nb + sl] =
            packh2(tact(acc[2 * j]), tact(acc[2 * j + 1]));
}

// ---------------- F6: 84-out GEMV over 60 h5 pairs, grid (nb/256, 6) --------
__global__ __launch_bounds__(256) void k_f6(
    const u32* __restrict__ h5p, const u32* __restrict__ wpk,
    const float* __restrict__ f6b, u32* __restrict__ h6p, int nb)
{
    const int sl = blockIdx.x * 256 + threadIdx.x;
    const int og = blockIdx.y;               // outputs og*14 .. og*14+13
    const u32* wp = wpk + WPK_F6 + og * 14 * 60;
    float acc[14];
    #pragma unroll
    for (int o = 0; o < 14; ++o) acc[o] = f6b[og * 14 + o];
    #pragma unroll 4
    for (int i = 0; i < 60; ++i) {
        const u32 v = h5p[(size_t)i * nb + sl];
        #pragma unroll
        for (int o = 0; o < 14; ++o)
            acc[o] = dot2(v, wp[o * 60 + i], acc[o]);    // uniform -> s_load
    }
    #pragma unroll
    for (int j = 0; j < 7; ++j)
        h6p[(size_t)(og * 7 + j) * nb + sl] =
            packh2(tact(acc[2 * j]), tact(acc[2 * j + 1]));
}

// ---------------- RBF head, grid (nb/256, 5): 2 classes per block -----------
__global__ __launch_bounds__(256) void k_rbf(
    const u32* __restrict__ h6p, const float* __restrict__ rbf,
    float* __restrict__ out, int nb)
{
    const int sl = blockIdx.x * 256 + threadIdx.x;
    const int gy = blockIdx.y;
    float hv[84];
    #pragma unroll
    for (int i = 0; i < 42; ++i) {
        const u32 v = h6p[(size_t)i * nb + sl];
        hv[2 * i]     = f16lo(v);
        hv[2 * i + 1] = f16hi(v);
    }
    #pragma unroll
    for (int a = 0; a < 2; ++a) {
        const int c = 2 * gy + a;
        float acc = 0.0f;
        #pragma unroll 4
        for (int i = 0; i < 84; ++i) {
            float d = hv[i] - rbf[c * 84 + i];   // uniform -> s_load
            acc += d * d;
        }
        out[(size_t)sl * 10 + c] = acc;
    }
}

extern "C" void kernel_launch(void* const* d_in, const int* in_sizes, int n_in,
                              void* d_out, int out_size, void* d_ws, size_t ws_size,
                              hipStream_t stream)
{
    const float* x    = (const float*)d_in[0];
    const float* w1   = (const float*)d_in[1];
    const float* b1   = (const float*)d_in[2];
    const float* s2w  = (const float*)d_in[3];
    const float* s2b  = (const float*)d_in[4];
    const float* w3   = (const float*)d_in[5];
    const float* b3   = (const float*)d_in[6];
    const float* s4w  = (const float*)d_in[7];
    const float* s4b  = (const float*)d_in[8];
    const float* w5   = (const float*)d_in[9];
    const float* b5   = (const float*)d_in[10];
    const float* f6w  = (const float*)d_in[11];
    const float* f6b  = (const float*)d_in[12];
    const float* rbfw = (const float*)d_in[13];
    float* out = (float*)d_out;
    char* ws = (char*)d_ws;

    // Weight pack at the tail of d_out (dead until k_rbf; k_rbf never reads
    // it and rewrites every byte of out at the end of each plan/chunk order).
    u32* WPK = (u32*)((char*)d_out +
                      (((size_t)out_size - (size_t)(WPK_N * 4)) & ~(size_t)7));
    k_wpack<<<dim3((WPK_N + 255) / 256), 256, 0, stream>>>(w1, w3, w5, f6w, WPK);

    if (ws_size >= 55312384) {
        // ---- Plan A: full-batch tail (10 dispatches) ----
        u32* S2P = (u32*)(ws);                       // 38,535,168 B (cells)
        u32* XP  = (u32*)(ws + 38535168);            // 16,777,216 B (front)
        u32* S4P = (u32*)(ws + 38535168);            // 15,728,640 B (after front)
        u32* H5P = (u32*)(ws);                       //  3,932,160 B (after c3s4)
        u32* H6P = (u32*)(ws + 4194304);             //  2,752,512 B
        for (int c = 0; c < 2; ++c) {
            k_tr  <<<dim3(128, 16), 256, 0, stream>>>(x + (size_t)c * 8192 * 1024, XP);
            k_c1s2m<<<dim3(128, 14), 256, 0, stream>>>(XP, WPK, b1, s2w, s2b,
                                                       S2P + (size_t)c * 16384,
                                                       8192, 16384);
        }
        k_c3s4m<<<dim3(256, 5), 256, 0, stream>>>(S2P, WPK, b3, s4w, s4b, S4P, 16384);
        k_c5  <<<dim3(64, 12), 256, 0, stream>>>(S4P, WPK, b5, H5P, 16384);
        k_f6  <<<dim3(64, 6), 256, 0, stream>>>(H5P, WPK, f6b, H6P, 16384);
        k_rbf <<<dim3(64, 5), 256, 0, stream>>>(H6P, rbfw, out, 16384);
    } else {
        // ---- Plan B: 2 chunks (13 dispatches) ----
        u32* XP  = (u32*)(ws);                       // 16,777,216 B
        u32* S2P = (u32*)(ws + 16777216);            // 19,267,584 B
        u32* S4P = (u32*)(ws);                       //  7,864,320 B (XP dead)
        u32* H5P = (u32*)(ws + 7864320);             //  1,966,080 B
        u32* H6P = (u32*)(ws + 9830400);             //  1,376,256 B
        for (int c = 0; c < 2; ++c) {
            k_tr  <<<dim3(128, 16), 256, 0, stream>>>(x + (size_t)c * 8192 * 1024, XP);
            k_c1s2m<<<dim3(128, 14), 256, 0, stream>>>(XP, WPK, b1, s2w, s2b,
                                                       S2P, 8192, 8192);
            k_c3s4m<<<dim3(128, 5), 256, 0, stream>>>(S2P, WPK, b3, s4w, s4b, S4P, 8192);
            k_c5  <<<dim3(32, 12), 256, 0, stream>>>(S4P, WPK, b5, H5P, 8192);
            k_f6  <<<dim3(32, 6), 256, 0, stream>>>(H5P, WPK, f6b, H6P, 8192);
            k_rbf <<<dim3(32, 5), 256, 0, stream>>>(H6P, rbfw, out + (size_t)c * 8192 * 10, 8192);
        }
    }
}